// Round 1
// baseline (563.221 us; speedup 1.0000x reference)
//
#include <hip/hip_runtime.h>
#include <hip/hip_bf16.h>

// Round 13: certificate-gated zero-stream.
// absmax==0.0 => reference output is identically zero on this input: every
// softmax weight w_i <= e^{tmax}/S < lambda, hard-shrink kills all, l1=0,
// w/max(l1,eps)=0, read=0.  The old kernel proved this the expensive way
// (full MFMA logits + 134M exps overlapped with the zero-stream).
// Jensen/AM-GM gives a cheap per-row certificate:
//   S = sum_i e^{t_i} >= 4096 * e^{tbar},  tbar = (2/4096) <x_hat, M>,
//   M = sum_i m_hat_i  (precomputed, 64 floats).
//   tmax <= 2  =>  w_max <= e^{2 - tbar}/4096 <= 0.0025  iff  tbar >= -0.3263.
// Test threshold -0.28 (margin 0.046 >> fp32/atomic-order error ~1e-4).
// Real data: |tbar| <~ 2*||M||/4096 ~ 0.031 -> every row passes by ~10x.
// Clean path = pure write roofline: 545 MB zeros ~ 87 us @ 6.3 TB/s.
// Blocks with any failing row fall back to the exact MFMA path (3 passes
// over the swizzled B strips; never triggered on this distribution).
// Zero-stores are drained by __syncthreads (implicit vmcnt(0)) before the
// fallback overwrites them -- same ordering argument as R12.

#define NM 4096
#define HD 64
#define NROWS 32768  // 16*2048

typedef short bf16x8 __attribute__((ext_vector_type(8)));
typedef float f32x4  __attribute__((ext_vector_type(4)));

// ---- prep: normalized x rows -> bf16 [row][k], scale folded in ----
__global__ __launch_bounds__(256) void prep_rows(const float* __restrict__ src,
                                                 ushort* __restrict__ dst,
                                                 float scale,
                                                 float* __restrict__ Mv) {
    // zero the M accumulator before prep_m_swz runs (stream order)
    if (blockIdx.x == 0 && threadIdx.x < 64) Mv[threadIdx.x] = 0.0f;
    const int wave = threadIdx.x >> 6, lane = threadIdx.x & 63;
    const long row = (long)blockIdx.x * 4 + wave;
    float v = src[row * HD + lane];
    float s = v * v;
#pragma unroll
    for (int o = 32; o; o >>= 1) s += __shfl_xor(s, o, 64);
    const float inv = scale / fmaxf(sqrtf(s), 1e-12f);
    __hip_bfloat16 h = __float2bfloat16(v * inv);
    dst[row * HD + lane] = *reinterpret_cast<ushort*>(&h);
}

// ---- prep: normalized memories -> swizzled MFMA B-frags + M = sum(m_hat) ----
__global__ __launch_bounds__(256) void prep_m_swz(const float* __restrict__ mem,
                                                  ushort* __restrict__ mbs,
                                                  float* __restrict__ Mv) {
    __shared__ float sM[4][64];
    const int wave = threadIdx.x >> 6, lane = threadIdx.x & 63;
    const int row = blockIdx.x * 4 + wave;   // n
    float v = mem[row * HD + lane];          // k = lane
    float s = v * v;
#pragma unroll
    for (int o = 32; o; o >>= 1) s += __shfl_xor(s, o, 64);
    const float inv = 1.0f / fmaxf(sqrtf(s), 1e-12f);
    const float nv = v * inv;
    __hip_bfloat16 h = __float2bfloat16(nv);
    const int t = row >> 4, c = row & 15;
    const int k = lane;
    const int f = k >> 5, q = (k >> 3) & 3, j = k & 7;
    mbs[(long)t * 1024 + f * 512 + (q * 16 + c) * 8 + j] =
        *reinterpret_cast<ushort*>(&h);
    // block-level reduction of m_hat, then one atomicAdd per component
    sM[wave][lane] = nv;
    __syncthreads();
    if (wave == 0)
        atomicAdd(&Mv[lane],
                  sM[0][lane] + sM[1][lane] + sM[2][lane] + sM[3][lane]);
}

// A-frag: lane holds xb[m0+(lane&15)][q*8..+7], q=lane>>4.
// C/D: col = lane&15, row = q*4 + reg   [verified layout, learn_hip m89/m91].
__global__ __launch_bounds__(256, 4) void k_zero(const float* __restrict__ x,
                                                 const float* __restrict__ Mv,
                                                 const ushort* __restrict__ xb,
                                                 const ushort* __restrict__ mbs,
                                                 const float* __restrict__ mem,
                                                 float* __restrict__ out_w,
                                                 float* __restrict__ out_read) {
    const int tid = threadIdx.x;
    const int wv = tid >> 6, lane = tid & 63;   // wv 0..3
    const int m0 = blockIdx.x * 16;

    __shared__ float sS[4][16];
    __shared__ float sL[4][16];
    __shared__ int   sFail[4];
    __shared__ float sred[4][16][64];   // fallback read partials, 16 KB

    // ---- Phase 0: per-row certificate (16-lane groups, 4 rows/wave) ----
    // pass  <=>  <x,M> >= -0.28 * (4096/2) * max(||x||, eps)
    {
        const int r16 = lane >> 4;           // 0..3
        const int k16 = lane & 15;
        const long row = (long)m0 + wv * 4 + r16;
        const float4 xv = *(const float4*)(x + row * HD + k16 * 4);
        const float4 mv = *(const float4*)(Mv + k16 * 4);
        float dot = xv.x * mv.x + xv.y * mv.y + xv.z * mv.z + xv.w * mv.w;
        float nn  = xv.x * xv.x + xv.y * xv.y + xv.z * xv.z + xv.w * xv.w;
#pragma unroll
        for (int o = 1; o < 16; o <<= 1) {
            dot += __shfl_xor(dot, o, 64);
            nn  += __shfl_xor(nn,  o, 64);
        }
        const bool pass = dot >= -573.44f * fmaxf(sqrtf(nn), 1e-12f);
        const unsigned long long bal = __ballot(!pass);
        if (lane == 0) sFail[wv] = (bal != 0ull);
    }

    // ---- Phase 1: stream zeros (the mandatory 545 MB) ----
    const float4 z4 = make_float4(0.0f, 0.0f, 0.0f, 0.0f);
    float4* base = (float4*)(out_w + (long)m0 * NM);   // 16384 float4
#pragma unroll 8
    for (int it = 0; it < 64; it++)
        base[it * 256 + tid] = z4;                     // 4 KB/iter, coalesced
    ((float4*)(out_read + (long)m0 * HD))[tid] = z4;   // 256 float4

    __syncthreads();   // drains zero stores (implicit vmcnt(0)); publishes sFail
    if (!(sFail[0] | sFail[1] | sFail[2] | sFail[3])) return;  // common case

    // ================= rare exact path (whole block) =================
    const int q = lane >> 4, c = lane & 15;
    const int nbase = wv * 1024;
    const bf16x8 a0 = *(const bf16x8*)(xb + (long)(m0 + c) * HD + q * 8);
    const bf16x8 a1 = *(const bf16x8*)(xb + (long)(m0 + c) * HD + q * 8 + 32);
    const ushort* mstrip = mbs + (long)(wv * 64) * 1024;   // wave's 64 chunks

    // P1: softmax denominator
    float sm[4] = {0.0f, 0.0f, 0.0f, 0.0f};
    for (int i = 0; i < 64; i++) {
        const ushort* mc = mstrip + (long)i * 1024 + lane * 8;
        const bf16x8 b0 = *(const bf16x8*)(mc);
        const bf16x8 b1 = *(const bf16x8*)(mc + 512);
        f32x4 t = {0.0f, 0.0f, 0.0f, 0.0f};
        t = __builtin_amdgcn_mfma_f32_16x16x32_bf16(a0, b0, t, 0, 0, 0);
        t = __builtin_amdgcn_mfma_f32_16x16x32_bf16(a1, b1, t, 0, 0, 0);
#pragma unroll
        for (int r = 0; r < 4; r++) sm[r] += __expf(t[r]);
    }
#pragma unroll
    for (int o = 1; o < 16; o <<= 1)
#pragma unroll
        for (int r = 0; r < 4; r++) sm[r] += __shfl_xor(sm[r], o, 64);
    if (c == 0)
#pragma unroll
        for (int r = 0; r < 4; r++) sS[wv][q * 4 + r] = sm[r];
    __syncthreads();
    float rS[4];
#pragma unroll
    for (int r = 0; r < 4; r++)
        rS[r] = 1.0f / (sS[0][q * 4 + r] + sS[1][q * 4 + r] +
                        sS[2][q * 4 + r] + sS[3][q * 4 + r]);

    // P2: shrink L1 norm
    float l1[4] = {0.0f, 0.0f, 0.0f, 0.0f};
    for (int i = 0; i < 64; i++) {
        const ushort* mc = mstrip + (long)i * 1024 + lane * 8;
        const bf16x8 b0 = *(const bf16x8*)(mc);
        const bf16x8 b1 = *(const bf16x8*)(mc + 512);
        f32x4 t = {0.0f, 0.0f, 0.0f, 0.0f};
        t = __builtin_amdgcn_mfma_f32_16x16x32_bf16(a0, b0, t, 0, 0, 0);
        t = __builtin_amdgcn_mfma_f32_16x16x32_bf16(a1, b1, t, 0, 0, 0);
#pragma unroll
        for (int r = 0; r < 4; r++) {
            float w = __expf(t[r]) * rS[r];
            float d = w - 0.0025f;
            l1[r] += __fdividef(fmaxf(d, 0.0f) * w, fabsf(d) + 1e-12f);
        }
    }
#pragma unroll
    for (int o = 1; o < 16; o <<= 1)
#pragma unroll
        for (int r = 0; r < 4; r++) l1[r] += __shfl_xor(l1[r], o, 64);
    if (c == 0)
#pragma unroll
        for (int r = 0; r < 4; r++) sL[wv][q * 4 + r] = l1[r];
    __syncthreads();
    float rL[4];
#pragma unroll
    for (int r = 0; r < 4; r++)
        rL[r] = 1.0f / fmaxf(sL[0][q * 4 + r] + sL[1][q * 4 + r] +
                             sL[2][q * 4 + r] + sL[3][q * 4 + r], 1e-12f);

    // P3: exact recompute + store (overwrites drained zeros) + read accum
    float racc[16];
#pragma unroll
    for (int r = 0; r < 16; r++) racc[r] = 0.0f;
    float* wbase = out_w + (long)(m0 + q * 4) * NM + c;
    for (int i = 0; i < 64; i++) {
        const int n0 = nbase + i * 16;
        const ushort* mc = mstrip + (long)i * 1024 + lane * 8;
        const bf16x8 b0 = *(const bf16x8*)(mc);
        const bf16x8 b1 = *(const bf16x8*)(mc + 512);
        f32x4 t = {0.0f, 0.0f, 0.0f, 0.0f};
        t = __builtin_amdgcn_mfma_f32_16x16x32_bf16(a0, b0, t, 0, 0, 0);
        t = __builtin_amdgcn_mfma_f32_16x16x32_bf16(a1, b1, t, 0, 0, 0);
        float wf[4];
#pragma unroll
        for (int r = 0; r < 4; r++) {
            float w  = __expf(t[r]) * rS[r];
            float d  = w - 0.0025f;
            float sh = __fdividef(fmaxf(d, 0.0f) * w, fabsf(d) + 1e-12f);
            wf[r] = sh * rL[r];
            wbase[(long)r * NM + n0] = wf[r];
        }
        const bool nz = (wf[0] != 0.0f) | (wf[1] != 0.0f) |
                        (wf[2] != 0.0f) | (wf[3] != 0.0f);
        unsigned long long mask = __ballot(nz);
        while (mask) {
            const int j = __ffsll((long long)mask) - 1;
            mask &= (mask - 1);
            const int qj = j >> 4, cj = j & 15;
            float b0v = __shfl(wf[0], j, 64), b1v = __shfl(wf[1], j, 64);
            float b2v = __shfl(wf[2], j, 64), b3v = __shfl(wf[3], j, 64);
            const float mv = mem[(long)(n0 + cj) * HD + lane];
            switch (qj) {  // wave-uniform branch
                case 0: racc[0]  += b0v * mv; racc[1]  += b1v * mv;
                        racc[2]  += b2v * mv; racc[3]  += b3v * mv; break;
                case 1: racc[4]  += b0v * mv; racc[5]  += b1v * mv;
                        racc[6]  += b2v * mv; racc[7]  += b3v * mv; break;
                case 2: racc[8]  += b0v * mv; racc[9]  += b1v * mv;
                        racc[10] += b2v * mv; racc[11] += b3v * mv; break;
                default: racc[12] += b0v * mv; racc[13] += b1v * mv;
                         racc[14] += b2v * mv; racc[15] += b3v * mv; break;
            }
        }
    }

    // combine read partials across waves, overwrite out_read
#pragma unroll
    for (int r = 0; r < 16; r++) sred[wv][r][lane] = racc[r];
    __syncthreads();
#pragma unroll
    for (int rr = 0; rr < 4; rr++) {
        const int row = wv * 4 + rr;
        const float v = sred[0][row][lane] + sred[1][row][lane] +
                        sred[2][row][lane] + sred[3][row][lane];
        out_read[(long)(m0 + row) * HD + lane] = v;
    }
}

extern "C" void kernel_launch(void* const* d_in, const int* in_sizes, int n_in,
                              void* d_out, int out_size, void* d_ws, size_t ws_size,
                              hipStream_t stream) {
    const float* x   = (const float*)d_in[0];
    const float* mem = (const float*)d_in[1];
    ushort* xb       = (ushort*)d_ws;                  // 4 MB
    ushort* mbs      = xb + (long)NROWS * HD;          // 512 KB (swizzled B)
    float*  Mv       = (float*)(mbs + (long)NM * HD);  // 256 B, 16B-aligned
    float* out_read  = (float*)d_out;                  // [32768*64]
    float* out_w     = out_read + (long)NROWS * HD;    // [32768*4096]

    prep_rows<<<NROWS / 4, 256, 0, stream>>>(x, xb, 2.0f, Mv);  // 1/T folded
    prep_m_swz<<<NM / 4, 256, 0, stream>>>(mem, mbs, Mv);
    k_zero<<<NROWS / 16, 256, 0, stream>>>(x, Mv, xb, mbs, mem, out_w, out_read);
}

// Round 2
// 561.317 us; speedup vs baseline: 1.0034x; 1.0034x over previous
//
#include <hip/hip_runtime.h>
#include <hip/hip_bf16.h>

// Round 14: barrier-free certificate-gated zero-stream.
// absmax==0.0: reference output is identically zero on this input (all
// softmax weights < shrink lambda).  Jensen/AM-GM certificate per row:
//   S = sum_i e^{t_i} >= 4096*e^{tbar},  tbar = (2/4096)<x_hat, M>,
//   M = sum_i m_hat_i;  tmax <= 2  =>  w_max <= e^{2-tbar}/4096 <= 0.0025
//   iff tbar >= -0.3263.  Test at -0.28 (margin 0.046 >> fp32 error ~1e-5).
// R13 regression root-cause: __syncthreads after the zero-stream forced a
// per-block vmcnt(0) write-ack drain before exit -> store-pipeline bubbles
// at block-generation boundaries.  R14: the certificate is evaluated in
// prep_rows (x_hat and ||x|| already in registers there) and published as
// one fail byte per row.  k_zero: uniform 16-byte flag load -> branch ->
// pure coalesced zero-stream -> s_endpgm with stores in flight.  No
// barrier, no LDS, no shuffle in the common path -- structurally identical
// to the harness fill kernel (6.2 TB/s).
// Dirty blocks (never on this distribution) run the exact MFMA path which
// writes EVERY output element itself (no pre-zeroing needed).

#define NM 4096
#define HD 64
#define NROWS 32768  // 16*2048

typedef short bf16x8 __attribute__((ext_vector_type(8)));
typedef float f32x4  __attribute__((ext_vector_type(4)));

// ---- zero the M accumulator (atomicAdd target) ----
__global__ void zeroM(float* __restrict__ Mv) { Mv[threadIdx.x] = 0.0f; }

// ---- prep: normalized memories -> swizzled MFMA B-frags + M = sum(m_hat) ----
__global__ __launch_bounds__(256) void prep_m_swz(const float* __restrict__ mem,
                                                  ushort* __restrict__ mbs,
                                                  float* __restrict__ Mv) {
    __shared__ float sM[4][64];
    const int wave = threadIdx.x >> 6, lane = threadIdx.x & 63;
    const int row = blockIdx.x * 4 + wave;   // n
    float v = mem[row * HD + lane];          // k = lane
    float s = v * v;
#pragma unroll
    for (int o = 32; o; o >>= 1) s += __shfl_xor(s, o, 64);
    const float inv = 1.0f / fmaxf(sqrtf(s), 1e-12f);
    const float nv = v * inv;
    __hip_bfloat16 h = __float2bfloat16(nv);
    const int t = row >> 4, c = row & 15;
    const int k = lane;
    const int f = k >> 5, q = (k >> 3) & 3, j = k & 7;
    mbs[(long)t * 1024 + f * 512 + (q * 16 + c) * 8 + j] =
        *reinterpret_cast<ushort*>(&h);
    sM[wave][lane] = nv;
    __syncthreads();
    if (wave == 0)
        atomicAdd(&Mv[lane],
                  sM[0][lane] + sM[1][lane] + sM[2][lane] + sM[3][lane]);
}

// ---- prep: normalized x rows -> bf16 (1/T folded) + per-row certificate ----
// pass  <=>  <x, M> >= -0.28 * (4096/2) * max(||x||, eps)
__global__ __launch_bounds__(256) void prep_rows(const float* __restrict__ src,
                                                 ushort* __restrict__ dst,
                                                 const float* __restrict__ Mv,
                                                 unsigned char* __restrict__ fail) {
    const int wave = threadIdx.x >> 6, lane = threadIdx.x & 63;
    const long row = (long)blockIdx.x * 4 + wave;
    float v = src[row * HD + lane];
    float s = v * v;
    float d = v * Mv[lane];
#pragma unroll
    for (int o = 32; o; o >>= 1) {
        s += __shfl_xor(s, o, 64);
        d += __shfl_xor(d, o, 64);
    }
    const float nrm = fmaxf(sqrtf(s), 1e-12f);
    const float inv = 2.0f / nrm;
    __hip_bfloat16 h = __float2bfloat16(v * inv);
    dst[row * HD + lane] = *reinterpret_cast<ushort*>(&h);
    if (lane == 0) fail[row] = (d >= -573.44f * nrm) ? 0 : 1;
}

// A-frag: lane holds xb[m0+(lane&15)][q*8..+7], q=lane>>4.
// C/D: col = lane&15, row = q*4 + reg   [verified layout, learn_hip m89/m91].
__global__ __launch_bounds__(256, 4) void k_zero(const unsigned char* __restrict__ fail,
                                                 const ushort* __restrict__ xb,
                                                 const ushort* __restrict__ mbs,
                                                 const float* __restrict__ mem,
                                                 float* __restrict__ out_w,
                                                 float* __restrict__ out_read) {
    const int tid = threadIdx.x;
    const int m0 = blockIdx.x * 16;

    // uniform per-block flag check (16 bytes, L1/scalar broadcast)
    const uint4 fw = *reinterpret_cast<const uint4*>(fail + m0);
    if ((fw.x | fw.y | fw.z | fw.w) == 0u) {
        // ---- clean path (common): pure zero-stream, no barrier, no drain ----
        const float4 z4 = make_float4(0.0f, 0.0f, 0.0f, 0.0f);
        ((float4*)(out_read + (long)m0 * HD))[tid] = z4;   // 4 KB/block
        float4* base = (float4*)(out_w + (long)m0 * NM);   // 16384 float4
#pragma unroll 8
        for (int it = 0; it < 64; it++)
            base[it * 256 + tid] = z4;                     // 4 KB/iter, coalesced
        return;  // s_endpgm with stores in flight
    }

    // ================= rare exact path (whole block, sole writer) ==========
    const int wv = tid >> 6, lane = tid & 63;
    const int q = lane >> 4, c = lane & 15;
    const int nbase = wv * 1024;

    __shared__ float sS[4][16];
    __shared__ float sL[4][16];
    __shared__ float sred[4][16][64];   // read partials, 16 KB

    const bf16x8 a0 = *(const bf16x8*)(xb + (long)(m0 + c) * HD + q * 8);
    const bf16x8 a1 = *(const bf16x8*)(xb + (long)(m0 + c) * HD + q * 8 + 32);
    const ushort* mstrip = mbs + (long)(wv * 64) * 1024;   // wave's 64 chunks

    // P1: softmax denominator
    float sm[4] = {0.0f, 0.0f, 0.0f, 0.0f};
    for (int i = 0; i < 64; i++) {
        const ushort* mc = mstrip + (long)i * 1024 + lane * 8;
        const bf16x8 b0 = *(const bf16x8*)(mc);
        const bf16x8 b1 = *(const bf16x8*)(mc + 512);
        f32x4 t = {0.0f, 0.0f, 0.0f, 0.0f};
        t = __builtin_amdgcn_mfma_f32_16x16x32_bf16(a0, b0, t, 0, 0, 0);
        t = __builtin_amdgcn_mfma_f32_16x16x32_bf16(a1, b1, t, 0, 0, 0);
#pragma unroll
        for (int r = 0; r < 4; r++) sm[r] += __expf(t[r]);
    }
#pragma unroll
    for (int o = 1; o < 16; o <<= 1)
#pragma unroll
        for (int r = 0; r < 4; r++) sm[r] += __shfl_xor(sm[r], o, 64);
    if (c == 0)
#pragma unroll
        for (int r = 0; r < 4; r++) sS[wv][q * 4 + r] = sm[r];
    __syncthreads();
    float rS[4];
#pragma unroll
    for (int r = 0; r < 4; r++)
        rS[r] = 1.0f / (sS[0][q * 4 + r] + sS[1][q * 4 + r] +
                        sS[2][q * 4 + r] + sS[3][q * 4 + r]);

    // P2: shrink L1 norm
    float l1[4] = {0.0f, 0.0f, 0.0f, 0.0f};
    for (int i = 0; i < 64; i++) {
        const ushort* mc = mstrip + (long)i * 1024 + lane * 8;
        const bf16x8 b0 = *(const bf16x8*)(mc);
        const bf16x8 b1 = *(const bf16x8*)(mc + 512);
        f32x4 t = {0.0f, 0.0f, 0.0f, 0.0f};
        t = __builtin_amdgcn_mfma_f32_16x16x32_bf16(a0, b0, t, 0, 0, 0);
        t = __builtin_amdgcn_mfma_f32_16x16x32_bf16(a1, b1, t, 0, 0, 0);
#pragma unroll
        for (int r = 0; r < 4; r++) {
            float w = __expf(t[r]) * rS[r];
            float d = w - 0.0025f;
            l1[r] += __fdividef(fmaxf(d, 0.0f) * w, fabsf(d) + 1e-12f);
        }
    }
#pragma unroll
    for (int o = 1; o < 16; o <<= 1)
#pragma unroll
        for (int r = 0; r < 4; r++) l1[r] += __shfl_xor(l1[r], o, 64);
    if (c == 0)
#pragma unroll
        for (int r = 0; r < 4; r++) sL[wv][q * 4 + r] = l1[r];
    __syncthreads();
    float rL[4];
#pragma unroll
    for (int r = 0; r < 4; r++)
        rL[r] = 1.0f / fmaxf(sL[0][q * 4 + r] + sL[1][q * 4 + r] +
                             sL[2][q * 4 + r] + sL[3][q * 4 + r], 1e-12f);

    // P3: exact recompute, store ALL weights (incl. zeros), read accum
    float racc[16];
#pragma unroll
    for (int r = 0; r < 16; r++) racc[r] = 0.0f;
    float* wbase = out_w + (long)(m0 + q * 4) * NM + c;
    for (int i = 0; i < 64; i++) {
        const int n0 = nbase + i * 16;
        const ushort* mc = mstrip + (long)i * 1024 + lane * 8;
        const bf16x8 b0 = *(const bf16x8*)(mc);
        const bf16x8 b1 = *(const bf16x8*)(mc + 512);
        f32x4 t = {0.0f, 0.0f, 0.0f, 0.0f};
        t = __builtin_amdgcn_mfma_f32_16x16x32_bf16(a0, b0, t, 0, 0, 0);
        t = __builtin_amdgcn_mfma_f32_16x16x32_bf16(a1, b1, t, 0, 0, 0);
        float wf[4];
#pragma unroll
        for (int r = 0; r < 4; r++) {
            float w  = __expf(t[r]) * rS[r];
            float d  = w - 0.0025f;
            float sh = __fdividef(fmaxf(d, 0.0f) * w, fabsf(d) + 1e-12f);
            wf[r] = sh * rL[r];
            wbase[(long)r * NM + n0] = wf[r];
        }
        const bool nz = (wf[0] != 0.0f) | (wf[1] != 0.0f) |
                        (wf[2] != 0.0f) | (wf[3] != 0.0f);
        unsigned long long mask = __ballot(nz);
        while (mask) {
            const int j = __ffsll((long long)mask) - 1;
            mask &= (mask - 1);
            const int qj = j >> 4, cj = j & 15;
            float b0v = __shfl(wf[0], j, 64), b1v = __shfl(wf[1], j, 64);
            float b2v = __shfl(wf[2], j, 64), b3v = __shfl(wf[3], j, 64);
            const float mv = mem[(long)(n0 + cj) * HD + lane];
            switch (qj) {  // wave-uniform branch
                case 0: racc[0]  += b0v * mv; racc[1]  += b1v * mv;
                        racc[2]  += b2v * mv; racc[3]  += b3v * mv; break;
                case 1: racc[4]  += b0v * mv; racc[5]  += b1v * mv;
                        racc[6]  += b2v * mv; racc[7]  += b3v * mv; break;
                case 2: racc[8]  += b0v * mv; racc[9]  += b1v * mv;
                        racc[10] += b2v * mv; racc[11] += b3v * mv; break;
                default: racc[12] += b0v * mv; racc[13] += b1v * mv;
                         racc[14] += b2v * mv; racc[15] += b3v * mv; break;
            }
        }
    }

    // combine read partials across waves, write out_read
#pragma unroll
    for (int r = 0; r < 16; r++) sred[wv][r][lane] = racc[r];
    __syncthreads();
#pragma unroll
    for (int rr = 0; rr < 4; rr++) {
        const int row = wv * 4 + rr;
        const float v = sred[0][row][lane] + sred[1][row][lane] +
                        sred[2][row][lane] + sred[3][row][lane];
        out_read[(long)(m0 + row) * HD + lane] = v;
    }
}

extern "C" void kernel_launch(void* const* d_in, const int* in_sizes, int n_in,
                              void* d_out, int out_size, void* d_ws, size_t ws_size,
                              hipStream_t stream) {
    const float* x   = (const float*)d_in[0];
    const float* mem = (const float*)d_in[1];
    ushort* xb       = (ushort*)d_ws;                    // 4 MB
    ushort* mbs      = xb + (long)NROWS * HD;            // 512 KB (swizzled B)
    float*  Mv       = (float*)(mbs + (long)NM * HD);    // 256 B, 16B-aligned
    unsigned char* fail = (unsigned char*)(Mv + 64);     // 32 KB, 16B-aligned
    float* out_read  = (float*)d_out;                    // [32768*64]
    float* out_w     = out_read + (long)NROWS * HD;      // [32768*4096]

    zeroM<<<1, 64, 0, stream>>>(Mv);
    prep_m_swz<<<NM / 4, 256, 0, stream>>>(mem, mbs, Mv);
    prep_rows<<<NROWS / 4, 256, 0, stream>>>(x, xb, Mv, fail);
    k_zero<<<NROWS / 16, 256, 0, stream>>>(fail, xb, mbs, mem, out_w, out_read);
}

// Round 3
// 538.917 us; speedup vs baseline: 1.0451x; 1.0416x over previous
//
#include <hip/hip_runtime.h>

// Round 15: two-dispatch certificate + zero-stream, per-wave granularity.
// absmax==0.0: the reference output is identically zero on this input.
// Jensen/AM-GM certificate per row:  S >= 4096*e^{tbar},
// tbar = (2/4096)<x_hat, M>, M = sum_i m_hat_i;  tmax <= 2  =>
// w_max <= e^{2-tbar}/4096 <= lambda=0.0025 iff tbar >= -0.3263.
// Test at -0.28 (margin 0.046 >> fp32 error ~1e-4).
// R14 post-mortem: chain was 4 serialized dispatches (~10us gap each) and
// 12 MB of prep traffic consumed only by the never-taken fallback.  R15:
//   k_m    (64 blocks):  P[b][k] = sum of 64 normalized memories (no
//                        atomics -> no zeroing dispatch needed).
//   k_zero (2048 blocks): per WAVE: reduce P (16 loads + 8 shfl) ->
//                        certify own 4 rows -> stream 64KB+1KB of zeros ->
//                        s_endpgm with stores in flight.  No LDS, no
//                        barrier, no post-store drain anywhere.
// Waves with a failing row run a self-contained exact scalar path
// (reads mem directly; slow but never taken on this distribution).

#define NM 4096
#define HD 64
#define NROWS 32768  // 16*2048

// ---- k_m: block b writes P[b][0..63] = sum_{i in b*64..+63} m_hat_i ----
__global__ __launch_bounds__(256) void k_m(const float* __restrict__ mem,
                                           float* __restrict__ P) {
    __shared__ float sM[4][64];
    const int wave = threadIdx.x >> 6, lane = threadIdx.x & 63;
    float acc = 0.0f;
#pragma unroll
    for (int s = 0; s < 16; s++) {
        const int i = blockIdx.x * 64 + wave * 16 + s;
        const float v = mem[i * HD + lane];
        float ss = v * v;
#pragma unroll
        for (int o = 32; o; o >>= 1) ss += __shfl_xor(ss, o, 64);
        acc += v / fmaxf(sqrtf(ss), 1e-12f);
    }
    sM[wave][lane] = acc;
    __syncthreads();
    if (wave == 0)
        P[blockIdx.x * 64 + lane] =
            sM[0][lane] + sM[1][lane] + sM[2][lane] + sM[3][lane];
}

// ---- k_zero: certificate + zero-stream, one wave owns 4 rows ----
__global__ __launch_bounds__(256) void k_zero(const float* __restrict__ x,
                                              const float* __restrict__ P,
                                              const float* __restrict__ mem,
                                              float* __restrict__ out_w,
                                              float* __restrict__ out_read) {
    const int tid = threadIdx.x;
    const int wv = tid >> 6, lane = tid & 63;
    const long rowbase = (long)blockIdx.x * 16 + wv * 4;   // 4 rows per wave
    const int r16 = lane >> 4, k16 = lane & 15;

    // M reduction: each 16-lane group sums 16 partial blocks, then combine.
    float4 mv = make_float4(0.0f, 0.0f, 0.0f, 0.0f);
#pragma unroll
    for (int b = 0; b < 16; b++) {
        const float4 p = *(const float4*)(P + (r16 * 16 + b) * 64 + k16 * 4);
        mv.x += p.x; mv.y += p.y; mv.z += p.z; mv.w += p.w;
    }
#pragma unroll
    for (int o = 16; o < 64; o <<= 1) {
        mv.x += __shfl_xor(mv.x, o, 64);
        mv.y += __shfl_xor(mv.y, o, 64);
        mv.z += __shfl_xor(mv.z, o, 64);
        mv.w += __shfl_xor(mv.w, o, 64);
    }

    // certificate for row rowbase + r16:  <x,M> >= -573.44 * max(||x||,eps)
    const long crow = rowbase + r16;
    const float4 xv = *(const float4*)(x + crow * HD + k16 * 4);
    float dot = xv.x * mv.x + xv.y * mv.y + xv.z * mv.z + xv.w * mv.w;
    float nn  = xv.x * xv.x + xv.y * xv.y + xv.z * xv.z + xv.w * xv.w;
#pragma unroll
    for (int o = 1; o < 16; o <<= 1) {
        dot += __shfl_xor(dot, o, 64);
        nn  += __shfl_xor(nn,  o, 64);
    }
    const bool pass = dot >= -573.44f * fmaxf(sqrtf(nn), 1e-12f);

    if (__ballot(!pass) == 0ull) {
        // ---- clean (common): pure zero-stream, no barrier, no drain ----
        const float4 z4 = make_float4(0.0f, 0.0f, 0.0f, 0.0f);
        ((float4*)(out_read + rowbase * HD))[lane] = z4;   // 4 rows = 1 KB
        float4* base = (float4*)(out_w + rowbase * NM);    // 4 rows = 64 KB
#pragma unroll 8
        for (int it = 0; it < 64; it++)
            base[it * 64 + lane] = z4;                     // 1 KB/instr
        return;  // s_endpgm with stores in flight
    }

    // ===== dirty wave (never on this distribution): exact scalar path =====
    for (int r = 0; r < 4; r++) {
        const long rw = rowbase + r;
        const float v = x[rw * HD + lane];
        float ss = v * v;
#pragma unroll
        for (int o = 32; o; o >>= 1) ss += __shfl_xor(ss, o, 64);
        const float xh = v * (2.0f / fmaxf(sqrtf(ss), 1e-12f));  // 2*xhat[lane]

        // pass 1: softmax denominator
        float S = 0.0f;
        for (int j = 0; j < 64; j++) {
            const int i = j * 64 + lane;
            float dp = 0.0f, nm = 0.0f;
            for (int k = 0; k < 64; k++) {
                const float mk = mem[(long)i * HD + k];
                dp += __shfl(xh, k, 64) * mk;
                nm += mk * mk;
            }
            const float t = dp / fmaxf(sqrtf(nm), 1e-12f);
            S += __expf(t);
        }
#pragma unroll
        for (int o = 1; o < 64; o <<= 1) S += __shfl_xor(S, o, 64);
        const float rS = 1.0f / S;

        // pass 2: shrink L1 norm
        float l1 = 0.0f;
        for (int j = 0; j < 64; j++) {
            const int i = j * 64 + lane;
            float dp = 0.0f, nm = 0.0f;
            for (int k = 0; k < 64; k++) {
                const float mk = mem[(long)i * HD + k];
                dp += __shfl(xh, k, 64) * mk;
                nm += mk * mk;
            }
            const float t = dp / fmaxf(sqrtf(nm), 1e-12f);
            const float w = __expf(t) * rS;
            const float d = w - 0.0025f;
            l1 += fmaxf(d, 0.0f) * w / (fabsf(d) + 1e-12f);
        }
#pragma unroll
        for (int o = 1; o < 64; o <<= 1) l1 += __shfl_xor(l1, o, 64);
        const float rL = 1.0f / fmaxf(l1, 1e-12f);

        // pass 3: weights + read accumulation (broadcast nonzeros)
        float rd = 0.0f;   // read component d = lane
        for (int j = 0; j < 64; j++) {
            const int i = j * 64 + lane;
            float dp = 0.0f, nm = 0.0f;
            for (int k = 0; k < 64; k++) {
                const float mk = mem[(long)i * HD + k];
                dp += __shfl(xh, k, 64) * mk;
                nm += mk * mk;
            }
            const float t = dp / fmaxf(sqrtf(nm), 1e-12f);
            const float w = __expf(t) * rS;
            const float d = w - 0.0025f;
            const float wf = fmaxf(d, 0.0f) * w / (fabsf(d) + 1e-12f) * rL;
            out_w[rw * NM + i] = wf;
            unsigned long long mball = __ballot(wf != 0.0f);
            while (mball) {
                const int L = __ffsll((long long)mball) - 1;
                mball &= mball - 1;
                const float wb = __shfl(wf, L, 64);
                rd += wb * mem[(long)(j * 64 + L) * HD + lane];
            }
        }
        out_read[rw * HD + lane] = rd;
    }
}

extern "C" void kernel_launch(void* const* d_in, const int* in_sizes, int n_in,
                              void* d_out, int out_size, void* d_ws, size_t ws_size,
                              hipStream_t stream) {
    const float* x   = (const float*)d_in[0];
    const float* mem = (const float*)d_in[1];
    float* P         = (float*)d_ws;                   // 64x64 partials, 16 KB
    float* out_read  = (float*)d_out;                  // [32768*64]
    float* out_w     = out_read + (long)NROWS * HD;    // [32768*4096]

    k_m<<<NM / 64, 256, 0, stream>>>(mem, P);
    k_zero<<<NROWS / 16, 256, 0, stream>>>(x, P, mem, out_w, out_read);
}